// Round 5
// baseline (212.362 us; speedup 1.0000x reference)
//
#include <hip/hip_runtime.h>
#include <math.h>

#define B_   8
#define C_   512
#define CQ   64
#define N_   4096
#define EPSF 1e-6f
#define LS   40    // LDS row stride (shorts) for 32-wide k chunks; 80 B = 5x16 B
#define LS2  72    // LDS row stride (shorts) for 64-wide k (K4); 144 B = 9x16 B

typedef short  shortx8 __attribute__((ext_vector_type(8)));
typedef short  shortx4 __attribute__((ext_vector_type(4)));
typedef short  shortx2 __attribute__((ext_vector_type(2)));
typedef float  floatx4 __attribute__((ext_vector_type(4)));

__device__ __forceinline__ short f2bf(float f) {
    unsigned u = __builtin_bit_cast(unsigned, f);
    u += 0x7FFFu + ((u >> 16) & 1u);
    return (short)(u >> 16);
}
__device__ __forceinline__ float bf2f(short h) {
    unsigned u = ((unsigned)(unsigned short)h) << 16;
    return __builtin_bit_cast(float, u);
}
__device__ __forceinline__ shortx8 ldf8(const short* p) {
    return *(const shortx8*)p;
}

// ---------------------------------------------------------------------------
// P: cast weights to bf16. Wqk[128][512] = [Wq;Wk], Wvb[512][512].
// ---------------------------------------------------------------------------
__global__ __launch_bounds__(256) void pcast(
    const float* __restrict__ Wq, const float* __restrict__ Wk,
    const float* __restrict__ Wv, short* __restrict__ Wqk, short* __restrict__ Wvb)
{
    int i = (blockIdx.x * 256 + threadIdx.x) * 4;
    float4 v; short* dst;
    if (i < 2 * CQ * C_) {
        const float* src = (i < CQ * C_) ? (Wq + i) : (Wk + i - CQ * C_);
        v = *(const float4*)src;
        dst = Wqk + i;
    } else {
        int j = i - 2 * CQ * C_;
        v = *(const float4*)(Wv + j);
        dst = Wvb + j;
    }
    const float* f = (const float*)&v;
    shortx4 o = { f2bf(f[0]), f2bf(f[1]), f2bf(f[2]), f2bf(f[3]) };
    *(shortx4*)dst = o;
}

// ---------------------------------------------------------------------------
// K1: QK = [Wq;Wk] @ x (bf16 MFMA), +bias, column L2-norm;
//     emits Qnt[b][n][m] bf16, Kn[b][m][n] bf16, Ksum (atomic).
// grid (nt=128, b=8) = 1024 blocks, block 256; n-tile = 32.
// waveM = Q/K half (64 m each), waveN = 16-n half.
// NOTE: launch_bounds kept at (256,2) — (256,4) would cap VGPR at 128 and can
// force spills -> scratch alloc at launch -> graph-capture abort (r4 crash).
// Occupancy comes from the small LDS (26 KB) + low VGPR use instead.
// ---------------------------------------------------------------------------
__global__ __launch_bounds__(256, 2) void k1_qk(
    const float* __restrict__ x, const short* __restrict__ Wqk,
    const float* __restrict__ bq, const float* __restrict__ bk,
    short* __restrict__ Qnt, short* __restrict__ Kn, float* __restrict__ Ksum)
{
    const int b   = blockIdx.y;
    const int n0  = blockIdx.x * 32;
    const int tid = threadIdx.x;
    const int lane = tid & 63, wid = tid >> 6;
    const int waveM = wid >> 1, waveN = wid & 1;
    const int quad = lane >> 4, ln = lane & 15;

    __shared__ short A_l[2][128][LS];   // [buf][m][k] Wqk bf16
    __shared__ short B_l[2][32][LS];    // [buf][n][k] x^T bf16
    __shared__ float bias_l[128];

    if (tid < 128) bias_l[tid] = (tid < 64) ? bq[tid] : bk[tid - 64];

    const int mA = tid >> 1, koA = (tid & 1) * 16;   // A: 128 m x 32 k
    const short* Asrc = Wqk + (size_t)mA * C_;
    const int kp = tid >> 4, nq = tid & 15;          // B: k rows {2kp,2kp+1}, n {2nq,2nq+1}
    const float* xb = x + (size_t)b * C_ * N_;

    shortx8 a0 = *(const shortx8*)(Asrc + koA);
    shortx8 a1 = *(const shortx8*)(Asrc + koA + 8);
    float2 r0, r1;
    {
        const float* Bs = xb + (size_t)(kp * 2) * N_ + n0 + nq * 2;
        r0 = *(const float2*)(Bs);
        r1 = *(const float2*)(Bs + N_);
    }

    auto stage = [&](int buf, shortx8 s0, shortx8 s1, float2 q0, float2 q1) {
        *(shortx8*)&A_l[buf][mA][koA]     = s0;
        *(shortx8*)&A_l[buf][mA][koA + 8] = s1;
        shortx2 t0 = { f2bf(q0.x), f2bf(q1.x) };   // n = 2nq,   k = 2kp..2kp+1
        shortx2 t1 = { f2bf(q0.y), f2bf(q1.y) };   // n = 2nq+1
        *(shortx2*)&B_l[buf][nq * 2][kp * 2]     = t0;
        *(shortx2*)&B_l[buf][nq * 2 + 1][kp * 2] = t1;
    };
    stage(0, a0, a1, r0, r1);
    __syncthreads();

    const floatx4 z4 = {0.f, 0.f, 0.f, 0.f};
    floatx4 acc[4] = {z4, z4, z4, z4};

    int cur = 0;
    for (int it = 0; it < 16; ++it) {
        shortx8 na0, na1; float2 nr0, nr1;
        if (it < 15) {
            const int k0 = (it + 1) * 32;
            na0 = *(const shortx8*)(Asrc + k0 + koA);
            na1 = *(const shortx8*)(Asrc + k0 + koA + 8);
            const float* Bs = xb + (size_t)(k0 + kp * 2) * N_ + n0 + nq * 2;
            nr0 = *(const float2*)(Bs);
            nr1 = *(const float2*)(Bs + N_);
        }
        shortx8 af[4];
#pragma unroll
        for (int mt = 0; mt < 4; mt++)
            af[mt] = ldf8(&A_l[cur][waveM * 64 + mt * 16 + ln][quad * 8]);
        shortx8 bf8 = ldf8(&B_l[cur][waveN * 16 + ln][quad * 8]);
#pragma unroll
        for (int mt = 0; mt < 4; mt++)
            acc[mt] = __builtin_amdgcn_mfma_f32_16x16x32_bf16(af[mt], bf8, acc[mt], 0, 0, 0);
        if (it < 15) stage(cur ^ 1, na0, na1, nr0, nr1);
        __syncthreads();
        cur ^= 1;
    }

    // bias
#pragma unroll
    for (int mt = 0; mt < 4; mt++)
#pragma unroll
        for (int r = 0; r < 4; r++)
            acc[mt][r] += bias_l[waveM * 64 + mt * 16 + quad * 4 + r];

    // column L2 normalize (wave's 64 rows are exactly Q or exactly K)
    {
        float s = 0.f;
#pragma unroll
        for (int mt = 0; mt < 4; mt++)
#pragma unroll
            for (int r = 0; r < 4; r++) s += acc[mt][r] * acc[mt][r];
        s += __shfl_xor(s, 16);
        s += __shfl_xor(s, 32);
        float inv = rsqrtf(s);
#pragma unroll
        for (int mt = 0; mt < 4; mt++)
#pragma unroll
            for (int r = 0; r < 4; r++) acc[mt][r] *= inv;
    }

    if (waveM == 0) {            // Qn^T [n][m]
        short* Qb = Qnt + (size_t)b * N_ * CQ;
        int n = n0 + waveN * 16 + ln;
#pragma unroll
        for (int mt = 0; mt < 4; mt++) {
            shortx4 v;
#pragma unroll
            for (int r = 0; r < 4; r++) v[r] = f2bf(acc[mt][r]);
            *(shortx4*)(Qb + (size_t)n * CQ + mt * 16 + quad * 4) = v;
        }
    } else {                     // Kn [m][n] + Ksum
        short* Kb = Kn + (size_t)b * CQ * N_;
        int n = n0 + waveN * 16 + ln;
#pragma unroll
        for (int mt = 0; mt < 4; mt++)
#pragma unroll
            for (int r = 0; r < 4; r++) {
                int m = mt * 16 + quad * 4 + r;
                float v = acc[mt][r];
                Kb[(size_t)m * N_ + n] = f2bf(v);
                float s = v;
                s += __shfl_xor(s, 1); s += __shfl_xor(s, 2);
                s += __shfl_xor(s, 4); s += __shfl_xor(s, 8);
                if (ln == 0) atomicAdd(&Ksum[b * CQ + m], s);
            }
    }
}

// ---------------------------------------------------------------------------
// K2: KX[m][j] += sum_n Kn[m][n]*x[j][n]; xsum[j] += sum_n x[j][n].
// grid (jt=8, ks=16, b=8) = 1024 blocks; block [64m][64j] over n=256.
// ---------------------------------------------------------------------------
__global__ __launch_bounds__(256, 2) void k2_kx(
    const float* __restrict__ x, const short* __restrict__ Kn,
    float* __restrict__ KX, float* __restrict__ xsum)
{
    const int jt = blockIdx.x, ks = blockIdx.y, b = blockIdx.z;
    const int j0 = jt * 64, nbase = ks * 256;
    const int tid = threadIdx.x;
    const int lane = tid & 63, wid = tid >> 6;
    const int quad = lane >> 4, ln = lane & 15;

    __shared__ short A_l[2][64][LS];    // Kn rows m
    __shared__ short B_l[2][64][LS];    // x rows j (bf16)

    const int rA = tid >> 2, oA = (tid & 3) * 8;
    const short* Kb = Kn + (size_t)b * CQ * N_;
    const float* xb = x + (size_t)b * C_ * N_;
    const short* As = Kb + (size_t)rA * N_ + nbase + oA;
    const float* Bs = xb + (size_t)(j0 + rA) * N_ + nbase + oA;

    float xsacc = 0.f;

    shortx8 aC = *(const shortx8*)As;
    float4 b0 = *(const float4*)(Bs);
    float4 b1 = *(const float4*)(Bs + 4);

    auto stage = [&](int buf, shortx8 a, float4 q0, float4 q1) {
        *(shortx8*)&A_l[buf][rA][oA] = a;
        const float* f0 = (const float*)&q0;
        const float* f1 = (const float*)&q1;
        shortx8 t;
#pragma unroll
        for (int i = 0; i < 4; i++) {
            t[i]     = f2bf(f0[i]); xsacc += f0[i];
            t[i + 4] = f2bf(f1[i]); xsacc += f1[i];
        }
        *(shortx8*)&B_l[buf][rA][oA] = t;
    };
    stage(0, aC, b0, b1);
    __syncthreads();

    const floatx4 z4 = {0.f, 0.f, 0.f, 0.f};
    floatx4 acc[4] = {z4, z4, z4, z4};

    int cur = 0;
    for (int it = 0; it < 8; ++it) {
        shortx8 aN; float4 n0v, n1v;
        if (it < 7) {
            const int off = (it + 1) * 32;
            aN  = *(const shortx8*)(As + off);
            n0v = *(const float4*)(Bs + off);
            n1v = *(const float4*)(Bs + off + 4);
        }
        shortx8 af[4];
#pragma unroll
        for (int mt = 0; mt < 4; mt++)
            af[mt] = ldf8(&A_l[cur][mt * 16 + ln][quad * 8]);
        shortx8 bf8 = ldf8(&B_l[cur][wid * 16 + ln][quad * 8]);
#pragma unroll
        for (int mt = 0; mt < 4; mt++)
            acc[mt] = __builtin_amdgcn_mfma_f32_16x16x32_bf16(af[mt], bf8, acc[mt], 0, 0, 0);
        if (it < 7) stage(cur ^ 1, aN, n0v, n1v);
        __syncthreads();
        cur ^= 1;
    }

    xsacc += __shfl_xor(xsacc, 1);
    xsacc += __shfl_xor(xsacc, 2);
    if ((tid & 3) == 0) atomicAdd(&xsum[b * C_ + j0 + rA], xsacc);

    float* KXb = KX + (size_t)b * CQ * C_;
#pragma unroll
    for (int mt = 0; mt < 4; mt++)
#pragma unroll
        for (int r = 0; r < 4; r++) {
            int m = mt * 16 + quad * 4 + r;
            atomicAdd(&KXb[(size_t)m * C_ + j0 + wid * 16 + ln], acc[mt][r]);
        }
}

// ---------------------------------------------------------------------------
// K3: Mt[c][m] = sum_j Wv[c][j]*KX[m][j] + Ksum[m]*bv[c]  (bf16 out, full j)
//     vs[c] = sum_j Wv[c][j]*xsum[j] + N*bv[c]
// grid (ct=8, b=8) = 64 blocks.
// ---------------------------------------------------------------------------
__global__ __launch_bounds__(256, 2) void k3_m(
    const float* __restrict__ KX, const short* __restrict__ Wvb,
    const float* __restrict__ bv, const float* __restrict__ Ksum,
    const float* __restrict__ xsum,
    short* __restrict__ Mt, float* __restrict__ vs)
{
    const int ct = blockIdx.x, b = blockIdx.y;
    const int c0 = ct * 64;
    const int tid = threadIdx.x;
    const int lane = tid & 63, wid = tid >> 6;
    const int quad = lane >> 4, ln = lane & 15;

    __shared__ short A_l[2][64][LS];   // Wv rows c
    __shared__ short B_l[2][64][LS];   // KX rows m (bf16)
    __shared__ float xsl[C_], Ksl[64], bvl[64], vsp[4][64];

    xsl[tid] = xsum[(size_t)b * C_ + tid];
    xsl[tid + 256] = xsum[(size_t)b * C_ + tid + 256];
    if (tid < 64) { Ksl[tid] = Ksum[b * CQ + tid]; bvl[tid] = bv[c0 + tid]; }

    const int rA = tid >> 2, oA = (tid & 3) * 8;
    const short* As = Wvb + (size_t)(c0 + rA) * C_ + oA;
    const float* Bs = KX + ((size_t)b * CQ + rA) * C_ + oA;

    shortx8 aC = *(const shortx8*)As;
    float4 b0 = *(const float4*)(Bs);
    float4 b1 = *(const float4*)(Bs + 4);

    auto stage = [&](int buf, shortx8 a, float4 q0, float4 q1) {
        *(shortx8*)&A_l[buf][rA][oA] = a;
        const float* f0 = (const float*)&q0;
        const float* f1 = (const float*)&q1;
        shortx8 t;
#pragma unroll
        for (int i = 0; i < 4; i++) { t[i] = f2bf(f0[i]); t[i + 4] = f2bf(f1[i]); }
        *(shortx8*)&B_l[buf][rA][oA] = t;
    };
    stage(0, aC, b0, b1);
    __syncthreads();

    const floatx4 z4 = {0.f, 0.f, 0.f, 0.f};
    floatx4 acc[4] = {z4, z4, z4, z4};
    float vsacc = 0.f;
    const int cv = tid & 63;

    int cur = 0;
    for (int it = 0; it < 16; ++it) {
        shortx8 aN; float4 n0v, n1v;
        if (it < 15) {
            const int off = (it + 1) * 32;
            aN  = *(const shortx8*)(As + off);
            n0v = *(const float4*)(Bs + off);
            n1v = *(const float4*)(Bs + off + 4);
        }
        shortx8 af[4];
#pragma unroll
        for (int ct2 = 0; ct2 < 4; ct2++)
            af[ct2] = ldf8(&A_l[cur][ct2 * 16 + ln][quad * 8]);
        shortx8 bf8 = ldf8(&B_l[cur][wid * 16 + ln][quad * 8]);
#pragma unroll
        for (int ct2 = 0; ct2 < 4; ct2++)
            acc[ct2] = __builtin_amdgcn_mfma_f32_16x16x32_bf16(af[ct2], bf8, acc[ct2], 0, 0, 0);
        // vs partial from staged Wv tile
#pragma unroll
        for (int jj = 0; jj < 8; jj++)
            vsacc += bf2f(A_l[cur][cv][wid * 8 + jj]) * xsl[it * 32 + wid * 8 + jj];
        if (it < 15) stage(cur ^ 1, aN, n0v, n1v);
        __syncthreads();
        cur ^= 1;
    }

    vsp[wid][cv] = vsacc;
    __syncthreads();
    if (tid < 64)
        vs[(size_t)b * C_ + c0 + tid] =
            vsp[0][tid] + vsp[1][tid] + vsp[2][tid] + vsp[3][tid] + (float)N_ * bvl[tid];

    const int m = wid * 16 + ln;
    const float ksm = Ksl[m];
    short* Mb = Mt + (size_t)b * C_ * CQ;
#pragma unroll
    for (int ct2 = 0; ct2 < 4; ct2++)
#pragma unroll
        for (int r = 0; r < 4; r++) {
            int c = ct2 * 16 + quad * 4 + r;
            Mb[(size_t)(c0 + c) * CQ + m] = f2bf(acc[ct2][r] + ksm * bvl[c]);
        }
}

// ---------------------------------------------------------------------------
// K4: ts[n] = 1/(N + Qn[:,n].(Ksum+eps));
//     out[c][n] = gamma*ts[n]*(vs[c] + sum_m Qn[m][n]*Mt[c][m])
// grid (nt=32, ct=4, b=8) = 1024 blocks, block 256; 128c x 128n, k=64.
// ---------------------------------------------------------------------------
__global__ __launch_bounds__(256, 2) void k4_out(
    const short* __restrict__ Qnt, const short* __restrict__ Mt,
    const float* __restrict__ vs, const float* __restrict__ Ksum,
    const float* __restrict__ gamma, float* __restrict__ out)
{
    const int nt = blockIdx.x, ct = blockIdx.y, b = blockIdx.z;
    const int n0 = nt * 128, c0 = ct * 128;
    const int tid = threadIdx.x;
    const int lane = tid & 63, wid = tid >> 6;
    const int waveC = wid >> 1, waveN = wid & 1;
    const int quad = lane >> 4, ln = lane & 15;

    __shared__ short A_l[128][LS2];   // Mt rows c (bf16), k=m
    __shared__ short B_l[128][LS2];   // Qnt rows n (bf16)
    __shared__ float tsl[128], vsl[128], Ks_l[64];

    {
        int c = tid >> 1, h = tid & 1;
        const short* src = Mt + ((size_t)b * C_ + c0 + c) * CQ + h * 32;
#pragma unroll
        for (int q = 0; q < 4; q++)
            *(shortx8*)&A_l[c][h * 32 + q * 8] = *(const shortx8*)(src + q * 8);
    }
    {
        int n = tid >> 1, h = tid & 1;
        const short* src = Qnt + ((size_t)b * N_ + n0 + n) * CQ + h * 32;
#pragma unroll
        for (int q = 0; q < 4; q++)
            *(shortx8*)&B_l[n][h * 32 + q * 8] = *(const shortx8*)(src + q * 8);
    }
    if (tid < 64)  Ks_l[tid] = Ksum[b * CQ + tid];
    if (tid < 128) vsl[tid]  = vs[(size_t)b * C_ + c0 + tid];
    __syncthreads();

    if (tid < 128) {
        const short* row = B_l[tid];
        float s = 0.f;
#pragma unroll
        for (int m = 0; m < 64; m++) s += bf2f(row[m]) * (Ks_l[m] + EPSF);
        tsl[tid] = 1.f / ((float)N_ + s);
    }
    __syncthreads();

    const floatx4 z4 = {0.f, 0.f, 0.f, 0.f};
    floatx4 acc[4][4];
#pragma unroll
    for (int i = 0; i < 4; i++)
#pragma unroll
        for (int j = 0; j < 4; j++) acc[i][j] = z4;

#pragma unroll
    for (int kc = 0; kc < 2; kc++) {
        shortx8 af[4];
#pragma unroll
        for (int ct2 = 0; ct2 < 4; ct2++)
            af[ct2] = ldf8(&A_l[waveC * 64 + ct2 * 16 + ln][kc * 32 + quad * 8]);
#pragma unroll
        for (int nt2 = 0; nt2 < 4; nt2++) {
            shortx8 bf8 = ldf8(&B_l[waveN * 64 + nt2 * 16 + ln][kc * 32 + quad * 8]);
#pragma unroll
            for (int ct2 = 0; ct2 < 4; ct2++)
                acc[ct2][nt2] = __builtin_amdgcn_mfma_f32_16x16x32_bf16(af[ct2], bf8, acc[ct2][nt2], 0, 0, 0);
        }
    }

    const float g = gamma[0];
    float* ob = out + (size_t)b * C_ * N_;
#pragma unroll
    for (int ct2 = 0; ct2 < 4; ct2++)
#pragma unroll
        for (int r = 0; r < 4; r++) {
            int cl = waveC * 64 + ct2 * 16 + quad * 4 + r;
            float vc = vsl[cl];
#pragma unroll
            for (int nt2 = 0; nt2 < 4; nt2++) {
                int nl = waveN * 64 + nt2 * 16 + ln;
                ob[(size_t)(c0 + cl) * N_ + n0 + nl] = g * tsl[nl] * (vc + acc[ct2][nt2][r]);
            }
        }
}

// ---------------------------------------------------------------------------
extern "C" void kernel_launch(void* const* d_in, const int* in_sizes, int n_in,
                              void* d_out, int out_size, void* d_ws, size_t ws_size,
                              hipStream_t stream)
{
    (void)in_sizes; (void)n_in; (void)out_size; (void)ws_size;
    const float* x     = (const float*)d_in[0];
    const float* Wq    = (const float*)d_in[1];
    const float* bq    = (const float*)d_in[2];
    const float* Wk    = (const float*)d_in[3];
    const float* bk    = (const float*)d_in[4];
    const float* Wv    = (const float*)d_in[5];
    const float* bv    = (const float*)d_in[6];
    const float* gamma = (const float*)d_in[7];
    float* out = (float*)d_out;

    short* Qnt = (short*)d_ws;                          // [8][4096][64] bf16
    short* Kn  = Qnt + (size_t)B_ * N_ * CQ;            // [8][64][4096] bf16
    float* Ksum = (float*)(Kn + (size_t)B_ * CQ * N_);  // [8][64]
    float* xsum = Ksum + B_ * CQ;                       // [8][512]
    float* KX   = xsum + B_ * C_;                       // [8][64][512]
    short* Mt   = (short*)(KX + (size_t)B_ * CQ * C_);  // [8][512][64] bf16
    float* vs   = (float*)(Mt + (size_t)B_ * C_ * CQ);  // [8][512]
    short* Wqk  = (short*)(vs + B_ * C_);               // [128][512] bf16
    short* Wvb  = Wqk + 2 * CQ * C_;                    // [512][512] bf16

    size_t zbytes = (size_t)(B_ * CQ + B_ * C_ + B_ * CQ * C_) * 4;
    hipMemsetAsync(Ksum, 0, zbytes, stream);

    pcast <<<dim3(320),       256, 0, stream>>>(Wq, Wk, Wv, Wqk, Wvb);
    k1_qk <<<dim3(128, 8),    256, 0, stream>>>(x, Wqk, bq, bk, Qnt, Kn, Ksum);
    k2_kx <<<dim3(8, 16, 8),  256, 0, stream>>>(x, Kn, KX, xsum);
    k3_m  <<<dim3(8, 8),      256, 0, stream>>>(KX, Wvb, bv, Ksum, xsum, Mt, vs);
    k4_out<<<dim3(32, 4, 8),  256, 0, stream>>>(Qnt, Mt, vs, Ksum, gamma, out);
}